// Round 1
// baseline (3650.961 us; speedup 1.0000x reference)
//
#include <hip/hip_runtime.h>
#include <hip/hip_bf16.h>

#define B_ 4096
#define K_ 64
#define N_ 100000
#define E_ 128
#define T_ 3

// ---------------------------------------------------------------------------
// Kernel 1: nodes_fusion[b] = relu(concat(node_emb[nodes[b]], node_prof[nodes[b]]) @ W_f + b_f)
// ---------------------------------------------------------------------------
__global__ __launch_bounds__(128)
void k_node_fusion(const int* __restrict__ nodes,
                   const float* __restrict__ node_emb,
                   const float* __restrict__ node_prof,
                   const float* __restrict__ W_f, const float* __restrict__ b_f,
                   float* __restrict__ nodes_fusion) {
    __shared__ float x[256];
    const int b = blockIdx.x;
    const int e = threadIdx.x;          // 0..127
    const int nd = nodes[b];
    x[e]       = node_emb[(size_t)nd * E_ + e];
    x[128 + e] = node_prof[(size_t)nd * E_ + e];
    __syncthreads();
    float acc = b_f[e];
#pragma unroll 8
    for (int i = 0; i < 256; ++i) acc = fmaf(x[i], W_f[i * E_ + e], acc);
    nodes_fusion[(size_t)b * E_ + e] = fmaxf(acc, 0.f);
}

// ---------------------------------------------------------------------------
// Kernel 2: per (t,b) block. 256 threads, K=64 neighbors in 4 chunks of 16.
//   nf   = relu([emb||prof]         @ W_f + b_f)   (gathered rows)
//   h1   = relu([nf || nodef]       @ Wa1 + ba1)
//   h2   = relu(h1                  @ Wa2 + ba2)
//   s    = h2 @ Wa3 + ba3 ; att = softmax_K(s)
//   type_agg[b,t] = relu((att^T nf) @ W1 + b1)
// Thread tile for GEMMs: 2 neighbors x 4 output features.
// ---------------------------------------------------------------------------
__global__ __launch_bounds__(256, 2)
void k_neigh_att(const int* __restrict__ neigh_idx,
                 const float* __restrict__ neigh_emb,
                 const float* __restrict__ neigh_prof,
                 const float* __restrict__ W_f, const float* __restrict__ b_f,
                 const float* __restrict__ Wa1, const float* __restrict__ ba1,
                 const float* __restrict__ Wa2, const float* __restrict__ ba2,
                 const float* __restrict__ Wa3, const float* __restrict__ ba3,
                 const float* __restrict__ W1,  const float* __restrict__ b1,
                 const float* __restrict__ nodes_fusion,
                 float* __restrict__ type_agg) {
    __shared__ float xg[16][256];     // gathered chunk inputs (emb||prof)
    __shared__ float nf[64][128];     // fused neighbor features (all K kept)
    __shared__ float h1[16][128];
    __shared__ float h2[16][128];
    __shared__ float nodef[128];
    __shared__ float sc[64];
    __shared__ float att_s[64];
    __shared__ float red2[2][128];

    const int b   = blockIdx.x;
    const int t   = blockIdx.y;
    const int tid = threadIdx.x;

    if (tid < 128) nodef[tid] = nodes_fusion[(size_t)b * E_ + tid];

    const float* emb_t   = neigh_emb  + (size_t)t * N_ * E_;
    const float* prof_t  = neigh_prof + (size_t)t * N_ * E_;
    const int*   idx_row = neigh_idx  + ((size_t)t * B_ + b) * K_;

    const int np = tid >> 5;      // 0..7  -> neighbors np and np+8 within chunk
    const int eg = tid & 31;      // 0..31 -> features e0..e0+3
    const int e0 = eg * 4;

    const int gr = tid >> 4;      // gather: row 0..15
    const int gq = tid & 15;      // gather: float4 slot

    float bf0[4], ba1v[4], ba2v[4];
#pragma unroll
    for (int j = 0; j < 4; ++j) {
        bf0[j]  = b_f[e0 + j];
        ba1v[j] = ba1[e0 + j];
        ba2v[j] = ba2[e0 + j];
    }

    for (int c = 0; c < 4; ++c) {
        // ---- gather 16 neighbor rows into xg = [emb(128) || prof(128)] ----
        {
            const int id = idx_row[c * 16 + gr];
            const float4* se = (const float4*)(emb_t  + (size_t)id * E_);
            const float4* sp = (const float4*)(prof_t + (size_t)id * E_);
            float4* dst = (float4*)(&xg[gr][0]);
            dst[gq]      = se[gq];
            dst[gq + 16] = se[gq + 16];
            dst[gq + 32] = sp[gq];
            dst[gq + 48] = sp[gq + 16];
        }
        __syncthreads();

        // ---- GEMM1: nf_chunk = relu(xg @ W_f + b_f), K=256 ----
        {
            float a0[4], a1[4];
#pragma unroll
            for (int j = 0; j < 4; ++j) { a0[j] = bf0[j]; a1[j] = bf0[j]; }
#pragma unroll 4
            for (int i = 0; i < 256; ++i) {
                const float4 w = *(const float4*)(W_f + i * E_ + e0);
                const float x0 = xg[np][i];
                const float x1 = xg[np + 8][i];
                a0[0] = fmaf(x0, w.x, a0[0]); a0[1] = fmaf(x0, w.y, a0[1]);
                a0[2] = fmaf(x0, w.z, a0[2]); a0[3] = fmaf(x0, w.w, a0[3]);
                a1[0] = fmaf(x1, w.x, a1[0]); a1[1] = fmaf(x1, w.y, a1[1]);
                a1[2] = fmaf(x1, w.z, a1[2]); a1[3] = fmaf(x1, w.w, a1[3]);
            }
#pragma unroll
            for (int j = 0; j < 4; ++j) {
                nf[c * 16 + np][e0 + j]     = fmaxf(a0[j], 0.f);
                nf[c * 16 + np + 8][e0 + j] = fmaxf(a1[j], 0.f);
            }
        }
        __syncthreads();

        // ---- GEMM2: h1 = relu([nf_chunk || nodef] @ Wa1 + ba1), K=256 ----
        {
            float a0[4], a1[4];
#pragma unroll
            for (int j = 0; j < 4; ++j) { a0[j] = ba1v[j]; a1[j] = ba1v[j]; }
            const float* nfr0 = &nf[c * 16 + np][0];
            const float* nfr1 = &nf[c * 16 + np + 8][0];
#pragma unroll 4
            for (int i = 0; i < 128; ++i) {
                const float4 w = *(const float4*)(Wa1 + i * E_ + e0);
                const float x0 = nfr0[i];
                const float x1 = nfr1[i];
                a0[0] = fmaf(x0, w.x, a0[0]); a0[1] = fmaf(x0, w.y, a0[1]);
                a0[2] = fmaf(x0, w.z, a0[2]); a0[3] = fmaf(x0, w.w, a0[3]);
                a1[0] = fmaf(x1, w.x, a1[0]); a1[1] = fmaf(x1, w.y, a1[1]);
                a1[2] = fmaf(x1, w.z, a1[2]); a1[3] = fmaf(x1, w.w, a1[3]);
            }
#pragma unroll 4
            for (int i = 0; i < 128; ++i) {
                const float4 w = *(const float4*)(Wa1 + (128 + i) * E_ + e0);
                const float xv = nodef[i];
                a0[0] = fmaf(xv, w.x, a0[0]); a0[1] = fmaf(xv, w.y, a0[1]);
                a0[2] = fmaf(xv, w.z, a0[2]); a0[3] = fmaf(xv, w.w, a0[3]);
                a1[0] = fmaf(xv, w.x, a1[0]); a1[1] = fmaf(xv, w.y, a1[1]);
                a1[2] = fmaf(xv, w.z, a1[2]); a1[3] = fmaf(xv, w.w, a1[3]);
            }
#pragma unroll
            for (int j = 0; j < 4; ++j) {
                h1[np][e0 + j]     = fmaxf(a0[j], 0.f);
                h1[np + 8][e0 + j] = fmaxf(a1[j], 0.f);
            }
        }
        __syncthreads();

        // ---- GEMM3: h2 = relu(h1 @ Wa2 + ba2), K=128 ----
        {
            float a0[4], a1[4];
#pragma unroll
            for (int j = 0; j < 4; ++j) { a0[j] = ba2v[j]; a1[j] = ba2v[j]; }
#pragma unroll 4
            for (int i = 0; i < 128; ++i) {
                const float4 w = *(const float4*)(Wa2 + i * E_ + e0);
                const float x0 = h1[np][i];
                const float x1 = h1[np + 8][i];
                a0[0] = fmaf(x0, w.x, a0[0]); a0[1] = fmaf(x0, w.y, a0[1]);
                a0[2] = fmaf(x0, w.z, a0[2]); a0[3] = fmaf(x0, w.w, a0[3]);
                a1[0] = fmaf(x1, w.x, a1[0]); a1[1] = fmaf(x1, w.y, a1[1]);
                a1[2] = fmaf(x1, w.z, a1[2]); a1[3] = fmaf(x1, w.w, a1[3]);
            }
#pragma unroll
            for (int j = 0; j < 4; ++j) {
                h2[np][e0 + j]     = fmaxf(a0[j], 0.f);
                h2[np + 8][e0 + j] = fmaxf(a1[j], 0.f);
            }
        }
        __syncthreads();

        // ---- scores: sc[n] = h2[n] . Wa3 + ba3 (16 lanes per neighbor) ----
        {
            const int n = tid >> 4;     // 0..15
            const int j = tid & 15;
            const float* hr = &h2[n][0];
            float p = 0.f;
#pragma unroll
            for (int i = 0; i < 8; ++i) p = fmaf(hr[j * 8 + i], Wa3[j * 8 + i], p);
            p += __shfl_xor(p, 1);
            p += __shfl_xor(p, 2);
            p += __shfl_xor(p, 4);
            p += __shfl_xor(p, 8);
            if (j == 0) sc[c * 16 + n] = p + ba3[0];
        }
        __syncthreads();
    }

    // ---- softmax over K=64 (wave 0) ----
    if (tid < 64) {
        const float v = sc[tid];
        float m = v;
#pragma unroll
        for (int o = 32; o > 0; o >>= 1) m = fmaxf(m, __shfl_xor(m, o));
        const float p = __expf(v - m);
        float s = p;
#pragma unroll
        for (int o = 32; o > 0; o >>= 1) s += __shfl_xor(s, o);
        att_s[tid] = p / s;
    }
    __syncthreads();

    // ---- agg[e] = sum_n att[n] * nf[n][e] ----
    {
        const int e    = tid & 127;
        const int half = tid >> 7;
        float a = 0.f;
#pragma unroll 8
        for (int n = 0; n < 32; ++n) {
            const int nn = half * 32 + n;
            a = fmaf(att_s[nn], nf[nn][e], a);
        }
        red2[half][e] = a;
    }
    __syncthreads();
    float* aggL = &xg[0][0];   // xg is dead, reuse
    if (tid < 128) aggL[tid] = red2[0][tid] + red2[1][tid];
    __syncthreads();

    // ---- type_agg[b, t*128 + e] = relu(agg @ W1 + b1) ----
    if (tid < 128) {
        float acc = b1[tid];
#pragma unroll 8
        for (int i = 0; i < 128; ++i) acc = fmaf(aggL[i], W1[i * E_ + tid], acc);
        type_agg[((size_t)b * T_ + t) * E_ + tid] = fmaxf(acc, 0.f);
    }
}

// ---------------------------------------------------------------------------
// Kernel 3: type softmax + final MLP + output head.
// ---------------------------------------------------------------------------
__global__ __launch_bounds__(128)
void k_final(const float* __restrict__ type_agg,
             const float* __restrict__ nodes_fusion,
             const float* __restrict__ Wt,
             const float* __restrict__ W2, const float* __restrict__ b2,
             const float* __restrict__ Wc, const float* __restrict__ bc,
             float* __restrict__ out, float* __restrict__ att_out) {
    __shared__ float ta[384];
    __shared__ float nfu[128];
    __shared__ float fin[128];
    __shared__ float hb[128];
    __shared__ float att[3];
    __shared__ float red[3][128];

    const int b = blockIdx.x;
    const int e = threadIdx.x;   // 0..127

    const float v0 = type_agg[(size_t)b * 384 + e];
    const float v1 = type_agg[(size_t)b * 384 + 128 + e];
    const float v2 = type_agg[(size_t)b * 384 + 256 + e];
    ta[e] = v0; ta[128 + e] = v1; ta[256 + e] = v2;
    nfu[e] = nodes_fusion[(size_t)b * E_ + e];

    // partial scores over types: rows e, 128+e, 256+e of Wt (384 x 3)
    float p0, p1, p2;
    {
        const float* w0 = Wt + (size_t)e * 3;
        const float* w1 = Wt + (size_t)(128 + e) * 3;
        const float* w2 = Wt + (size_t)(256 + e) * 3;
        p0 = v0 * w0[0] + v1 * w1[0] + v2 * w2[0];
        p1 = v0 * w0[1] + v1 * w1[1] + v2 * w2[1];
        p2 = v0 * w0[2] + v1 * w1[2] + v2 * w2[2];
    }
    red[0][e] = p0; red[1][e] = p1; red[2][e] = p2;
    __syncthreads();

    if (e < 3) {
        float s = 0.f;
        for (int i = 0; i < 128; ++i) s += red[e][i];
        red[e][0] = s;
    }
    __syncthreads();
    if (e == 0) {
        const float s0 = red[0][0], s1 = red[1][0], s2 = red[2][0];
        const float m  = fmaxf(s0, fmaxf(s1, s2));
        const float e0 = __expf(s0 - m), e1 = __expf(s1 - m), e2 = __expf(s2 - m);
        const float inv = 1.f / (e0 + e1 + e2);
        att[0] = e0 * inv; att[1] = e1 * inv; att[2] = e2 * inv;
    }
    __syncthreads();

    fin[e] = att[0] * ta[e] + att[1] * ta[128 + e] + att[2] * ta[256 + e];
    __syncthreads();

    // final = relu(fin @ W2 + b2)
    float acc = b2[e];
#pragma unroll 8
    for (int i = 0; i < 128; ++i) acc = fmaf(fin[i], W2[i * E_ + e], acc);
    hb[e] = fmaxf(acc, 0.f);
    __syncthreads();

    // out = relu([nfu || hb] @ Wc + bc)
    float acc2 = bc[e];
#pragma unroll 8
    for (int i = 0; i < 128; ++i) acc2 = fmaf(nfu[i], Wc[i * E_ + e], acc2);
#pragma unroll 8
    for (int i = 0; i < 128; ++i) acc2 = fmaf(hb[i], Wc[(128 + i) * E_ + e], acc2);
    out[(size_t)b * E_ + e] = fmaxf(acc2, 0.f);

    if (e < 3) att_out[(size_t)b * 3 + e] = att[e];
}

// ---------------------------------------------------------------------------
extern "C" void kernel_launch(void* const* d_in, const int* in_sizes, int n_in,
                              void* d_out, int out_size, void* d_ws, size_t ws_size,
                              hipStream_t stream) {
    const int*   nodes      = (const int*)d_in[0];
    const int*   neigh_idx  = (const int*)d_in[1];
    const float* node_emb   = (const float*)d_in[2];
    const float* node_prof  = (const float*)d_in[3];
    const float* neigh_emb  = (const float*)d_in[4];
    const float* neigh_prof = (const float*)d_in[5];
    const float* W_f = (const float*)d_in[6];  const float* b_f = (const float*)d_in[7];
    const float* Wa1 = (const float*)d_in[8];  const float* ba1 = (const float*)d_in[9];
    const float* Wa2 = (const float*)d_in[10]; const float* ba2 = (const float*)d_in[11];
    const float* Wa3 = (const float*)d_in[12]; const float* ba3 = (const float*)d_in[13];
    const float* W1  = (const float*)d_in[14]; const float* b1  = (const float*)d_in[15];
    const float* W2  = (const float*)d_in[16]; const float* b2  = (const float*)d_in[17];
    const float* Wc  = (const float*)d_in[18]; const float* bc  = (const float*)d_in[19];
    const float* Wt  = (const float*)d_in[20];

    float* out     = (float*)d_out;
    float* att_out = out + (size_t)B_ * E_;

    float* nodes_fusion = (float*)d_ws;                       // B*E floats
    float* type_agg     = nodes_fusion + (size_t)B_ * E_;     // B*T*E floats

    k_node_fusion<<<B_, 128, 0, stream>>>(nodes, node_emb, node_prof, W_f, b_f,
                                          nodes_fusion);
    k_neigh_att<<<dim3(B_, T_), 256, 0, stream>>>(neigh_idx, neigh_emb, neigh_prof,
                                                  W_f, b_f, Wa1, ba1, Wa2, ba2,
                                                  Wa3, ba3, W1, b1,
                                                  nodes_fusion, type_agg);
    k_final<<<B_, 128, 0, stream>>>(type_agg, nodes_fusion, Wt, W2, b2, Wc, bc,
                                    out, att_out);
}

// Round 2
// 490.446 us; speedup vs baseline: 7.4442x; 7.4442x over previous
//
#include <hip/hip_runtime.h>
#include <hip/hip_bf16.h>

#define B_ 4096
#define K_ 64
#define N_ 100000
#define E_ 128
#define T_ 3

typedef __bf16 bf16x8 __attribute__((ext_vector_type(8)));
typedef float  f32x4  __attribute__((ext_vector_type(4)));

// ---------------------------------------------------------------------------
// Kernel 0: transpose + bf16-convert the three GEMM weight matrices.
//   WtF [128][256] <- W_f [256][128]
//   Wa1t[128][128] <- Wa1[0:128][128] (top half; bottom half folded into node_pre)
//   Wa2t[128][128] <- Wa2 [128][128]
// ---------------------------------------------------------------------------
__global__ __launch_bounds__(256)
void k_prep(const float* __restrict__ W_f, const float* __restrict__ Wa1,
            const float* __restrict__ Wa2,
            __bf16* __restrict__ WtF, __bf16* __restrict__ Wa1t,
            __bf16* __restrict__ Wa2t) {
    const int n = blockIdx.x;      // 0..127 output row (= original col)
    const int k = threadIdx.x;
    if (blockIdx.y == 0) {
        WtF[n * 256 + k] = (__bf16)W_f[k * 128 + n];
    } else if (blockIdx.y == 1) {
        if (k < 128) Wa1t[n * 128 + k] = (__bf16)Wa1[k * 128 + n];
    } else {
        if (k < 128) Wa2t[n * 128 + k] = (__bf16)Wa2[k * 128 + n];
    }
}

// ---------------------------------------------------------------------------
// Kernel 1: nodes_fusion[b] = relu(concat(node_emb[nd], node_prof[nd]) @ W_f + b_f)
// ---------------------------------------------------------------------------
__global__ __launch_bounds__(128)
void k_node_fusion(const int* __restrict__ nodes,
                   const float* __restrict__ node_emb,
                   const float* __restrict__ node_prof,
                   const float* __restrict__ W_f, const float* __restrict__ b_f,
                   float* __restrict__ nodes_fusion) {
    __shared__ float x[256];
    const int b = blockIdx.x;
    const int e = threadIdx.x;          // 0..127
    const int nd = nodes[b];
    x[e]       = node_emb[(size_t)nd * E_ + e];
    x[128 + e] = node_prof[(size_t)nd * E_ + e];
    __syncthreads();
    float acc = b_f[e];
#pragma unroll 8
    for (int i = 0; i < 256; ++i) acc = fmaf(x[i], W_f[i * E_ + e], acc);
    nodes_fusion[(size_t)b * E_ + e] = fmaxf(acc, 0.f);
}

// ---------------------------------------------------------------------------
// Kernel 1b: node_pre[b][c] = ba1[c] + sum_i nodes_fusion[b][i] * Wa1[128+i][c]
// (row-constant half of the GEMM2 concat, computed once per b instead of
//  per (t,b,k) — removes half of GEMM2's K)
// ---------------------------------------------------------------------------
__global__ __launch_bounds__(128)
void k_node_pre(const float* __restrict__ nodes_fusion,
                const float* __restrict__ Wa1, const float* __restrict__ ba1,
                float* __restrict__ node_pre) {
    __shared__ float x[128];
    const int b = blockIdx.x;
    const int c = threadIdx.x;
    x[c] = nodes_fusion[(size_t)b * E_ + c];
    __syncthreads();
    float acc = ba1[c];
#pragma unroll 8
    for (int i = 0; i < 128; ++i) acc = fmaf(x[i], Wa1[(128 + i) * E_ + c], acc);
    node_pre[(size_t)b * E_ + c] = acc;
}

// ---------------------------------------------------------------------------
// Kernel 2 (hot): per (b,t) block, 4 waves. MFMA bf16 16x16x32.
//   X  = bf16(gather [emb||prof]) [64][256]      (LDS, padded stride 264)
//   NF = relu(X @ WtF^T + b_f)    [64][128] bf16 (LDS, stride 136)
//   H1 = relu(NF @ Wa1t^T + node_pre) -> into X buffer (stride 136)
//   scores = relu(H1 @ Wa2t^T + ba2) @ Wa3  (computed in epilogue, no H2 buf)
//   att = softmax_K(scores); agg = att^T NF; type_agg = relu(agg @ W1 + b1)
// Wave w owns output cols [32w, 32w+32) (2 N-tiles), all 4 M-tiles.
// ---------------------------------------------------------------------------
__global__ __launch_bounds__(256, 3)
void k_neigh_att(const int* __restrict__ neigh_idx,
                 const float* __restrict__ neigh_emb,
                 const float* __restrict__ neigh_prof,
                 const __bf16* __restrict__ WtF,
                 const __bf16* __restrict__ Wa1t,
                 const __bf16* __restrict__ Wa2t,
                 const float* __restrict__ b_f,
                 const float* __restrict__ ba2,
                 const float* __restrict__ Wa3, const float* __restrict__ ba3,
                 const float* __restrict__ W1,  const float* __restrict__ b1,
                 const float* __restrict__ node_pre,
                 float* __restrict__ type_agg) {
    __shared__ __bf16 Xl[64 * 264];     // 33792 B : X (K=256), later H1 (stride 136)
    __shared__ __bf16 NFl[64 * 136];    // 17408 B : fused neighbors (persist)
    __shared__ float  sc4[4 * 64];      // per-wave score partials; reused as aggL
    __shared__ float  att_s[64];
    __shared__ float  npre[128];
    __shared__ float  red2[2 * 128];

    const int b   = blockIdx.x;
    const int t   = blockIdx.y;
    const int tid = threadIdx.x;
    const int wid  = tid >> 6;          // wave 0..3
    const int lane = tid & 63;
    const int lr   = lane & 15;         // M-row (A) / N-col (B,D) within tile
    const int lk   = lane >> 4;         // k-group 0..3

    const float* emb_t   = neigh_emb  + (size_t)t * N_ * E_;
    const float* prof_t  = neigh_prof + (size_t)t * N_ * E_;
    const int*   idx_row = neigh_idx  + ((size_t)t * B_ + b) * K_;

    if (tid < 128) npre[tid] = node_pre[(size_t)b * E_ + tid];

    // ---- gather 64 rows, f32 -> bf16, into Xl [64][264] ----
    {
        const int grow = tid >> 2;                 // 0..63
        const int gp   = tid & 3;                  // quarter of the 256-col row
        const int id   = idx_row[grow];
        const float* srcb = (gp < 2) ? (emb_t + (size_t)id * E_)
                                     : (prof_t + (size_t)id * E_);
        const float4* s4 = (const float4*)(srcb + (gp & 1) * 64);
        __bf16* dst = &Xl[grow * 264 + gp * 64];
#pragma unroll
        for (int i = 0; i < 8; ++i) {
            const float4 u = s4[2 * i];
            const float4 v = s4[2 * i + 1];
            bf16x8 o;
            o[0] = (__bf16)u.x; o[1] = (__bf16)u.y; o[2] = (__bf16)u.z; o[3] = (__bf16)u.w;
            o[4] = (__bf16)v.x; o[5] = (__bf16)v.y; o[6] = (__bf16)v.z; o[7] = (__bf16)v.w;
            *(bf16x8*)(dst + i * 8) = o;
        }
    }
    __syncthreads();

    const int c0 = wid * 32 + lr;       // wave's first N-tile col
    const int c1 = c0 + 16;             // second N-tile col

    // ---- GEMM1: NF = relu(X @ W_f + b_f), K=256 (8 ksteps) ----
    {
        f32x4 acc[4][2] = {};
#pragma unroll
        for (int ks = 0; ks < 8; ++ks) {
            const bf16x8 bf0 = *(const bf16x8*)&WtF[c0 * 256 + ks * 32 + lk * 8];
            const bf16x8 bf1 = *(const bf16x8*)&WtF[c1 * 256 + ks * 32 + lk * 8];
#pragma unroll
            for (int mi = 0; mi < 4; ++mi) {
                const bf16x8 a = *(const bf16x8*)&Xl[(mi * 16 + lr) * 264 + ks * 32 + lk * 8];
                acc[mi][0] = __builtin_amdgcn_mfma_f32_16x16x32_bf16(a, bf0, acc[mi][0], 0, 0, 0);
                acc[mi][1] = __builtin_amdgcn_mfma_f32_16x16x32_bf16(a, bf1, acc[mi][1], 0, 0, 0);
            }
        }
        const float bc0 = b_f[c0], bc1 = b_f[c1];
#pragma unroll
        for (int mi = 0; mi < 4; ++mi)
#pragma unroll
            for (int j = 0; j < 4; ++j) {
                const int row = mi * 16 + lk * 4 + j;
                NFl[row * 136 + c0] = (__bf16)fmaxf(acc[mi][0][j] + bc0, 0.f);
                NFl[row * 136 + c1] = (__bf16)fmaxf(acc[mi][1][j] + bc1, 0.f);
            }
    }
    __syncthreads();

    // ---- GEMM2: H1 = relu(NF @ Wa1_top + node_pre), K=128 -> Xl (stride 136) ----
    __bf16* H1 = Xl;
    {
        f32x4 acc[4][2] = {};
#pragma unroll
        for (int ks = 0; ks < 4; ++ks) {
            const bf16x8 bf0 = *(const bf16x8*)&Wa1t[c0 * 128 + ks * 32 + lk * 8];
            const bf16x8 bf1 = *(const bf16x8*)&Wa1t[c1 * 128 + ks * 32 + lk * 8];
#pragma unroll
            for (int mi = 0; mi < 4; ++mi) {
                const bf16x8 a = *(const bf16x8*)&NFl[(mi * 16 + lr) * 136 + ks * 32 + lk * 8];
                acc[mi][0] = __builtin_amdgcn_mfma_f32_16x16x32_bf16(a, bf0, acc[mi][0], 0, 0, 0);
                acc[mi][1] = __builtin_amdgcn_mfma_f32_16x16x32_bf16(a, bf1, acc[mi][1], 0, 0, 0);
            }
        }
        const float p0 = npre[c0], p1 = npre[c1];
        __syncthreads();   // all waves done reading Xl (GEMM1 A) before H1 writes
#pragma unroll
        for (int mi = 0; mi < 4; ++mi)
#pragma unroll
            for (int j = 0; j < 4; ++j) {
                const int row = mi * 16 + lk * 4 + j;
                H1[row * 136 + c0] = (__bf16)fmaxf(acc[mi][0][j] + p0, 0.f);
                H1[row * 136 + c1] = (__bf16)fmaxf(acc[mi][1][j] + p1, 0.f);
            }
    }
    __syncthreads();

    // ---- GEMM3 + scores: s = relu(H1 @ Wa2 + ba2) @ Wa3 (epilogue reduce) ----
    {
        f32x4 acc[4][2] = {};
#pragma unroll
        for (int ks = 0; ks < 4; ++ks) {
            const bf16x8 bf0 = *(const bf16x8*)&Wa2t[c0 * 128 + ks * 32 + lk * 8];
            const bf16x8 bf1 = *(const bf16x8*)&Wa2t[c1 * 128 + ks * 32 + lk * 8];
#pragma unroll
            for (int mi = 0; mi < 4; ++mi) {
                const bf16x8 a = *(const bf16x8*)&H1[(mi * 16 + lr) * 136 + ks * 32 + lk * 8];
                acc[mi][0] = __builtin_amdgcn_mfma_f32_16x16x32_bf16(a, bf0, acc[mi][0], 0, 0, 0);
                acc[mi][1] = __builtin_amdgcn_mfma_f32_16x16x32_bf16(a, bf1, acc[mi][1], 0, 0, 0);
            }
        }
        const float w30 = Wa3[c0], w31 = Wa3[c1];
        const float a20 = ba2[c0], a21 = ba2[c1];
#pragma unroll
        for (int mi = 0; mi < 4; ++mi)
#pragma unroll
            for (int j = 0; j < 4; ++j) {
                float v = fmaxf(acc[mi][0][j] + a20, 0.f) * w30
                        + fmaxf(acc[mi][1][j] + a21, 0.f) * w31;
                v += __shfl_xor(v, 1);
                v += __shfl_xor(v, 2);
                v += __shfl_xor(v, 4);
                v += __shfl_xor(v, 8);
                if (lr == 0) sc4[wid * 64 + mi * 16 + lk * 4 + j] = v;
            }
    }
    __syncthreads();

    // ---- softmax over K=64 (wave 0) ----
    if (tid < 64) {
        const float v = sc4[tid] + sc4[64 + tid] + sc4[128 + tid] + sc4[192 + tid]
                      + ba3[0];
        float m = v;
#pragma unroll
        for (int o = 32; o > 0; o >>= 1) m = fmaxf(m, __shfl_xor(m, o));
        const float p = __expf(v - m);
        float s = p;
#pragma unroll
        for (int o = 32; o > 0; o >>= 1) s += __shfl_xor(s, o);
        att_s[tid] = p / s;
    }
    __syncthreads();

    // ---- agg[e] = sum_n att[n] * NF[n][e] ----
    {
        const int e    = tid & 127;
        const int half = tid >> 7;
        float a = 0.f;
#pragma unroll 8
        for (int n = 0; n < 32; ++n) {
            const int nn = half * 32 + n;
            a = fmaf(att_s[nn], (float)NFl[nn * 136 + e], a);
        }
        red2[half * 128 + e] = a;
    }
    __syncthreads();
    float* aggL = sc4;   // sc4 dead after softmax
    if (tid < 128) aggL[tid] = red2[tid] + red2[128 + tid];
    __syncthreads();

    // ---- type_agg[b, t*128 + e] = relu(agg @ W1 + b1) ----
    if (tid < 128) {
        float acc = b1[tid];
#pragma unroll 8
        for (int i = 0; i < 128; ++i) acc = fmaf(aggL[i], W1[i * E_ + tid], acc);
        type_agg[((size_t)b * T_ + t) * E_ + tid] = fmaxf(acc, 0.f);
    }
}

// ---------------------------------------------------------------------------
// Kernel 3: type softmax + final MLP + output head.
// ---------------------------------------------------------------------------
__global__ __launch_bounds__(128)
void k_final(const float* __restrict__ type_agg,
             const float* __restrict__ nodes_fusion,
             const float* __restrict__ Wt,
             const float* __restrict__ W2, const float* __restrict__ b2,
             const float* __restrict__ Wc, const float* __restrict__ bc,
             float* __restrict__ out, float* __restrict__ att_out) {
    __shared__ float ta[384];
    __shared__ float nfu[128];
    __shared__ float fin[128];
    __shared__ float hb[128];
    __shared__ float att[3];
    __shared__ float red[3][128];

    const int b = blockIdx.x;
    const int e = threadIdx.x;   // 0..127

    const float v0 = type_agg[(size_t)b * 384 + e];
    const float v1 = type_agg[(size_t)b * 384 + 128 + e];
    const float v2 = type_agg[(size_t)b * 384 + 256 + e];
    ta[e] = v0; ta[128 + e] = v1; ta[256 + e] = v2;
    nfu[e] = nodes_fusion[(size_t)b * E_ + e];

    float p0, p1, p2;
    {
        const float* w0 = Wt + (size_t)e * 3;
        const float* w1 = Wt + (size_t)(128 + e) * 3;
        const float* w2 = Wt + (size_t)(256 + e) * 3;
        p0 = v0 * w0[0] + v1 * w1[0] + v2 * w2[0];
        p1 = v0 * w0[1] + v1 * w1[1] + v2 * w2[1];
        p2 = v0 * w0[2] + v1 * w1[2] + v2 * w2[2];
    }
    red[0][e] = p0; red[1][e] = p1; red[2][e] = p2;
    __syncthreads();

    if (e < 3) {
        float s = 0.f;
        for (int i = 0; i < 128; ++i) s += red[e][i];
        red[e][0] = s;
    }
    __syncthreads();
    if (e == 0) {
        const float s0 = red[0][0], s1 = red[1][0], s2 = red[2][0];
        const float m  = fmaxf(s0, fmaxf(s1, s2));
        const float e0 = __expf(s0 - m), e1 = __expf(s1 - m), e2 = __expf(s2 - m);
        const float inv = 1.f / (e0 + e1 + e2);
        att[0] = e0 * inv; att[1] = e1 * inv; att[2] = e2 * inv;
    }
    __syncthreads();

    fin[e] = att[0] * ta[e] + att[1] * ta[128 + e] + att[2] * ta[256 + e];
    __syncthreads();

    float acc = b2[e];
#pragma unroll 8
    for (int i = 0; i < 128; ++i) acc = fmaf(fin[i], W2[i * E_ + e], acc);
    hb[e] = fmaxf(acc, 0.f);
    __syncthreads();

    float acc2 = bc[e];
#pragma unroll 8
    for (int i = 0; i < 128; ++i) acc2 = fmaf(nfu[i], Wc[i * E_ + e], acc2);
#pragma unroll 8
    for (int i = 0; i < 128; ++i) acc2 = fmaf(hb[i], Wc[(128 + i) * E_ + e], acc2);
    out[(size_t)b * E_ + e] = fmaxf(acc2, 0.f);

    if (e < 3) att_out[(size_t)b * 3 + e] = att[e];
}

// ---------------------------------------------------------------------------
extern "C" void kernel_launch(void* const* d_in, const int* in_sizes, int n_in,
                              void* d_out, int out_size, void* d_ws, size_t ws_size,
                              hipStream_t stream) {
    const int*   nodes      = (const int*)d_in[0];
    const int*   neigh_idx  = (const int*)d_in[1];
    const float* node_emb   = (const float*)d_in[2];
    const float* node_prof  = (const float*)d_in[3];
    const float* neigh_emb  = (const float*)d_in[4];
    const float* neigh_prof = (const float*)d_in[5];
    const float* W_f = (const float*)d_in[6];  const float* b_f = (const float*)d_in[7];
    const float* Wa1 = (const float*)d_in[8];  const float* ba1 = (const float*)d_in[9];
    const float* Wa2 = (const float*)d_in[10]; const float* ba2 = (const float*)d_in[11];
    const float* Wa3 = (const float*)d_in[12]; const float* ba3 = (const float*)d_in[13];
    const float* W1  = (const float*)d_in[14]; const float* b1  = (const float*)d_in[15];
    const float* W2  = (const float*)d_in[16]; const float* b2  = (const float*)d_in[17];
    const float* Wc  = (const float*)d_in[18]; const float* bc  = (const float*)d_in[19];
    const float* Wt  = (const float*)d_in[20];

    float* out     = (float*)d_out;
    float* att_out = out + (size_t)B_ * E_;

    char* ws = (char*)d_ws;
    float*  nodes_fusion = (float*)(ws);                    // B*E f32
    float*  type_agg     = (float*)(ws + 2097152);          // B*T*E f32
    float*  node_pre     = (float*)(ws + 8388608);          // B*E f32
    __bf16* WtF          = (__bf16*)(ws + 10485760);        // 128*256 bf16
    __bf16* Wa1t         = (__bf16*)(ws + 10551296);        // 128*128 bf16
    __bf16* Wa2t         = (__bf16*)(ws + 10584064);        // 128*128 bf16

    k_prep<<<dim3(128, 3), 256, 0, stream>>>(W_f, Wa1, Wa2, WtF, Wa1t, Wa2t);
    k_node_fusion<<<B_, 128, 0, stream>>>(nodes, node_emb, node_prof, W_f, b_f,
                                          nodes_fusion);
    k_node_pre<<<B_, 128, 0, stream>>>(nodes_fusion, Wa1, ba1, node_pre);
    k_neigh_att<<<dim3(B_, T_), 256, 0, stream>>>(neigh_idx, neigh_emb, neigh_prof,
                                                  WtF, Wa1t, Wa2t, b_f, ba2,
                                                  Wa3, ba3, W1, b1,
                                                  node_pre, type_agg);
    k_final<<<B_, 128, 0, stream>>>(type_agg, nodes_fusion, Wt, W2, b2, Wc, bc,
                                    out, att_out);
}